// Round 1
// baseline (6104.449 us; speedup 1.0000x reference)
//
#include <hip/hip_runtime.h>
#include <math.h>

constexpr int nB = 1024, nS = 30, nE = 300, nD = 512, nH = 8, nL = 4, nDK = 64;
constexpr int nTOK = nB * nS;  // 30720
constexpr float kSqrtD = 22.627416997969522f;       // sqrt(512)
constexpr float kPEc   = -0.03597789207803244f;     // -2*ln(10000)/512

// ---------------- embedding gather + input projection + posenc ----------------
constexpr int TPB_EMB = 8;
__global__ __launch_bounds__(256) void embed_kernel(
    const int* __restrict__ x, const float* __restrict__ emb,
    const float* __restrict__ W_in, const float* __restrict__ b_in,
    float* __restrict__ h) {
  const int tid = threadIdx.x;
  const int t0 = blockIdx.x * TPB_EMB;
  __shared__ float er[TPB_EMB][nE];
  for (int idx = tid; idx < TPB_EMB * nE; idx += 256) {
    int r = idx / nE, e = idx - r * nE;
    er[r][e] = emb[(size_t)x[t0 + r] * nE + e];
  }
  __syncthreads();
  for (int d = tid; d < nD; d += 256) {
    const float* w = W_in + (size_t)d * nE;
    float acc[TPB_EMB] = {};
    for (int e = 0; e < nE; e += 4) {
      const float4 wv = *(const float4*)(w + e);
#pragma unroll
      for (int r = 0; r < TPB_EMB; ++r) {
        const float4 ev = *(const float4*)&er[r][e];
        acc[r] += ev.x * wv.x + ev.y * wv.y + ev.z * wv.z + ev.w * wv.w;
      }
    }
    const float bias = b_in[d];
    const float dv = expf((float)(d >> 1) * kPEc);
#pragma unroll
    for (int r = 0; r < TPB_EMB; ++r) {
      const int t = t0 + r;
      const int s = t % nS;
      const float ang = (float)s * dv;
      const float pe = (d & 1) ? cosf(ang) : sinf(ang);
      h[(size_t)t * nD + d] = (acc[r] + bias) * kSqrtD + pe;
    }
  }
}

// ---------------- fused attention per (batch, head) ----------------
__global__ __launch_bounds__(256) void attn_kernel(
    const float* __restrict__ h, const int* __restrict__ mask,
    const float* __restrict__ Wq, const float* __restrict__ Wk,
    const float* __restrict__ Wv, float* __restrict__ out) {
  const int tid = threadIdx.x;
  const int b = blockIdx.x >> 3;
  const int hd = blockIdx.x & 7;

  __shared__ float xs[nS][68];
  __shared__ float wA[nDK][68];   // Wq, later Wv
  __shared__ float wB[nDK][68];   // Wk
  __shared__ float sQ[32][68];    // q
  __shared__ float sKV[32][68];   // k, later v
  __shared__ float ps[nS][33];    // scores / probs
  __shared__ int msk[32];

  // load x slice, Wq, Wk, mask
  for (int idx = tid; idx < nS * (nDK / 4); idx += 256) {  // 480 float4
    const int s = idx >> 4, c = (idx & 15) << 2;
    *(float4*)&xs[s][c] = *(const float4*)(h + ((size_t)(b * nS + s)) * nD + hd * nDK + c);
  }
  for (int idx = tid; idx < nDK * (nDK / 4); idx += 256) { // 1024 float4 each
    const int r = idx >> 4, c = (idx & 15) << 2;
    *(float4*)&wA[r][c] = *(const float4*)(Wq + r * nDK + c);
    *(float4*)&wB[r][c] = *(const float4*)(Wk + r * nDK + c);
  }
  if (tid < nS) msk[tid] = mask[b * nS + tid];
  __syncthreads();

  const int dg = tid & 15, sg = tid >> 4;
  const int d0 = dg << 2;
  const bool has2 = (sg + 16) < nS;

  // q, k projections (register-blocked 2 rows x 4 cols x 2 mats)
  {
    float aq0[4] = {}, aq1[4] = {}, ak0[4] = {}, ak1[4] = {};
#pragma unroll
    for (int k4 = 0; k4 < nDK; k4 += 4) {
      const float4 x0 = *(const float4*)&xs[sg][k4];
      const float4 x1 = has2 ? *(const float4*)&xs[sg + 16][k4] : make_float4(0.f, 0.f, 0.f, 0.f);
#pragma unroll
      for (int i = 0; i < 4; ++i) {
        const float4 wq4 = *(const float4*)&wA[d0 + i][k4];
        const float4 wk4 = *(const float4*)&wB[d0 + i][k4];
        aq0[i] += x0.x * wq4.x + x0.y * wq4.y + x0.z * wq4.z + x0.w * wq4.w;
        ak0[i] += x0.x * wk4.x + x0.y * wk4.y + x0.z * wk4.z + x0.w * wk4.w;
        aq1[i] += x1.x * wq4.x + x1.y * wq4.y + x1.z * wq4.z + x1.w * wq4.w;
        ak1[i] += x1.x * wk4.x + x1.y * wk4.y + x1.z * wk4.z + x1.w * wk4.w;
      }
    }
    *(float4*)&sQ[sg][d0]  = make_float4(aq0[0], aq0[1], aq0[2], aq0[3]);
    *(float4*)&sKV[sg][d0] = make_float4(ak0[0], ak0[1], ak0[2], ak0[3]);
    if (has2) {
      *(float4*)&sQ[sg + 16][d0]  = make_float4(aq1[0], aq1[1], aq1[2], aq1[3]);
      *(float4*)&sKV[sg + 16][d0] = make_float4(ak1[0], ak1[1], ak1[2], ak1[3]);
    }
  }
  __syncthreads();

  // prefetch Wv into registers (hides under scores+softmax)
  float4 wvreg[4];
#pragma unroll
  for (int i = 0; i < 4; ++i) {
    const int f4 = tid + 256 * i;
    wvreg[i] = *(const float4*)(Wv + (f4 << 2));
  }

  // scores = q k^T / 8, masked
  {
    const int i = tid >> 3, j0 = (tid & 7) << 2;
    if (i < nS) {
      float acc[4] = {};
#pragma unroll
      for (int d4 = 0; d4 < nDK; d4 += 4) {
        const float4 q4 = *(const float4*)&sQ[i][d4];
#pragma unroll
        for (int jj = 0; jj < 4; ++jj) {
          const float4 k4 = *(const float4*)&sKV[j0 + jj][d4];
          acc[jj] += q4.x * k4.x + q4.y * k4.y + q4.z * k4.z + q4.w * k4.w;
        }
      }
#pragma unroll
      for (int jj = 0; jj < 4; ++jj) {
        const int j = j0 + jj;
        if (j < nS) ps[i][j] = (msk[j] == 0) ? -1e9f : acc[jj] * 0.125f;
      }
    }
  }
  __syncthreads();

  // softmax: 8 lanes per row
  if (tid < nS * 8) {
    const int r = tid >> 3, c = tid & 7;
    float m = -1e30f;
    for (int j = c; j < nS; j += 8) m = fmaxf(m, ps[r][j]);
#pragma unroll
    for (int off = 1; off < 8; off <<= 1) m = fmaxf(m, __shfl_xor(m, off));
    float sum = 0.f;
    for (int j = c; j < nS; j += 8) {
      const float e = __expf(ps[r][j] - m);
      ps[r][j] = e;
      sum += e;
    }
#pragma unroll
    for (int off = 1; off < 8; off <<= 1) sum += __shfl_xor(sum, off);
    const float inv = 1.f / sum;
    for (int j = c; j < nS; j += 8) ps[r][j] *= inv;
  }
  __syncthreads();

  // Wv regs -> LDS (wA space; Wq is dead)
#pragma unroll
  for (int i = 0; i < 4; ++i) {
    const int f4 = tid + 256 * i;
    const int r = f4 >> 4, c = (f4 & 15) << 2;
    *(float4*)&wA[r][c] = wvreg[i];
  }
  __syncthreads();

  // v projection into sKV (k is dead)
  {
    float av0[4] = {}, av1[4] = {};
#pragma unroll
    for (int k4 = 0; k4 < nDK; k4 += 4) {
      const float4 x0 = *(const float4*)&xs[sg][k4];
      const float4 x1 = has2 ? *(const float4*)&xs[sg + 16][k4] : make_float4(0.f, 0.f, 0.f, 0.f);
#pragma unroll
      for (int i = 0; i < 4; ++i) {
        const float4 wv4 = *(const float4*)&wA[d0 + i][k4];
        av0[i] += x0.x * wv4.x + x0.y * wv4.y + x0.z * wv4.z + x0.w * wv4.w;
        av1[i] += x1.x * wv4.x + x1.y * wv4.y + x1.z * wv4.z + x1.w * wv4.w;
      }
    }
    *(float4*)&sKV[sg][d0] = make_float4(av0[0], av0[1], av0[2], av0[3]);
    if (has2) *(float4*)&sKV[sg + 16][d0] = make_float4(av1[0], av1[1], av1[2], av1[3]);
  }
  __syncthreads();

  // o = p @ v
  {
    float a0[4] = {}, a1[4] = {};
#pragma unroll
    for (int j = 0; j < nS; ++j) {
      const float4 vv = *(const float4*)&sKV[j][d0];
      const float p0 = ps[sg][j];
      const float p1 = has2 ? ps[sg + 16][j] : 0.f;
      a0[0] += p0 * vv.x; a0[1] += p0 * vv.y; a0[2] += p0 * vv.z; a0[3] += p0 * vv.w;
      a1[0] += p1 * vv.x; a1[1] += p1 * vv.y; a1[2] += p1 * vv.z; a1[3] += p1 * vv.w;
    }
    *(float4*)(out + ((size_t)(b * nS + sg)) * nD + hd * nDK + d0) =
        make_float4(a0[0], a0[1], a0[2], a0[3]);
    if (has2)
      *(float4*)(out + ((size_t)(b * nS + sg + 16)) * nD + hd * nDK + d0) =
          make_float4(a1[0], a1[1], a1[2], a1[3]);
  }
}

// ---------------- tiled NT GEMM: C[t,n] = sum_k A[t,k]*W[n,k] (+bias)(+resid) ----------------
__global__ __launch_bounds__(256) void gemm_nt_kernel(
    const float* __restrict__ A, const float* __restrict__ W,
    const float* __restrict__ bias, const float* __restrict__ resid,
    float* __restrict__ C) {
  __shared__ float As[16][68];
  __shared__ float Ws[16][68];
  const int tid = threadIdx.x;
  const int bm = blockIdx.x, bn = blockIdx.y;
  const int tx = tid & 15, ty = tid >> 4;
  const int lr = tid >> 2, lc = (tid & 3) << 2;
  const float* Ag = A + (size_t)(bm * 64 + lr) * nD + lc;
  const float* Wg = W + (size_t)(bn * 64 + lr) * nD + lc;
  float acc[4][4] = {};
  for (int k0 = 0; k0 < nD; k0 += 16) {
    const float4 av = *(const float4*)(Ag + k0);
    const float4 wv = *(const float4*)(Wg + k0);
    __syncthreads();
    As[lc + 0][lr] = av.x; As[lc + 1][lr] = av.y; As[lc + 2][lr] = av.z; As[lc + 3][lr] = av.w;
    Ws[lc + 0][lr] = wv.x; Ws[lc + 1][lr] = wv.y; Ws[lc + 2][lr] = wv.z; Ws[lc + 3][lr] = wv.w;
    __syncthreads();
#pragma unroll
    for (int k = 0; k < 16; ++k) {
      const float4 a = *(const float4*)&As[k][ty << 2];
      const float4 w = *(const float4*)&Ws[k][tx << 2];
      const float aa[4] = {a.x, a.y, a.z, a.w};
      const float ww[4] = {w.x, w.y, w.z, w.w};
#pragma unroll
      for (int i = 0; i < 4; ++i)
#pragma unroll
        for (int j = 0; j < 4; ++j)
          acc[i][j] += aa[i] * ww[j];
    }
  }
  const int gr0 = bm * 64 + (ty << 2);
  const int gc = bn * 64 + (tx << 2);
#pragma unroll
  for (int i = 0; i < 4; ++i) {
    const size_t off = (size_t)(gr0 + i) * nD + gc;
    float4 o = make_float4(acc[i][0], acc[i][1], acc[i][2], acc[i][3]);
    if (bias) { o.x += bias[gc]; o.y += bias[gc + 1]; o.z += bias[gc + 2]; o.w += bias[gc + 3]; }
    if (resid) {
      const float4 rs = *(const float4*)(resid + off);
      o.x += rs.x; o.y += rs.y; o.z += rs.z; o.w += rs.w;
    }
    *(float4*)(C + off) = o;
  }
}

// ---------------- row LayerNorm over D=512 ----------------
__global__ __launch_bounds__(256) void ln_kernel(
    const float* __restrict__ X, const float* __restrict__ g,
    const float* __restrict__ bta, float* __restrict__ Y) {
  const int t = blockIdx.x, tid = threadIdx.x;
  const float2 v = *(const float2*)(X + (size_t)t * nD + tid * 2);
  __shared__ float red[4];
  float s = v.x + v.y;
#pragma unroll
  for (int off = 32; off >= 1; off >>= 1) s += __shfl_down(s, off);
  if ((tid & 63) == 0) red[tid >> 6] = s;
  __syncthreads();
  const float mu = (red[0] + red[1] + red[2] + red[3]) * (1.0f / nD);
  const float e0 = v.x - mu, e1 = v.y - mu;
  float sq = e0 * e0 + e1 * e1;
  __syncthreads();
#pragma unroll
  for (int off = 32; off >= 1; off >>= 1) sq += __shfl_down(sq, off);
  if ((tid & 63) == 0) red[tid >> 6] = sq;
  __syncthreads();
  const float var = (red[0] + red[1] + red[2] + red[3]) * (1.0f / nD);
  const float inv = rsqrtf(var + 1e-5f);
  const float2 gg = *(const float2*)(g + tid * 2);
  const float2 bb = *(const float2*)(bta + tid * 2);
  float2 o;
  o.x = e0 * inv * gg.x + bb.x;
  o.y = e1 * inv * gg.y + bb.y;
  *(float2*)(Y + (size_t)t * nD + tid * 2) = o;
}

extern "C" void kernel_launch(void* const* d_in, const int* in_sizes, int n_in,
                              void* d_out, int out_size, void* d_ws, size_t ws_size,
                              hipStream_t stream) {
  const int*   x    = (const int*)d_in[0];
  const int*   mask = (const int*)d_in[1];
  const float* emb  = (const float*)d_in[2];
  const float* W_in = (const float*)d_in[3];
  const float* b_in = (const float*)d_in[4];
  const float* Wq   = (const float*)d_in[5];
  const float* Wk   = (const float*)d_in[6];
  const float* Wv   = (const float*)d_in[7];
  const float* Wo   = (const float*)d_in[8];
  const float* Wfc  = (const float*)d_in[9];
  const float* bfc  = (const float*)d_in[10];
  const float* g1   = (const float*)d_in[11];
  const float* be1  = (const float*)d_in[12];
  const float* g2   = (const float*)d_in[13];
  const float* be2  = (const float*)d_in[14];
  float* h   = (float*)d_out;   // h lives in d_out across layers
  float* ws0 = (float*)d_ws;    // attn-out / fc-out scratch (63 MB)

  embed_kernel<<<nTOK / TPB_EMB, 256, 0, stream>>>(x, emb, W_in, b_in, h);
  const dim3 ggrid(nTOK / 64, nD / 64);
  for (int l = 0; l < nL; ++l) {
    attn_kernel<<<nB * nH, 256, 0, stream>>>(
        h, mask, Wq + (size_t)l * nDK * nDK, Wk + (size_t)l * nDK * nDK,
        Wv + (size_t)l * nDK * nDK, ws0);
    // t1 = attn_out @ Wo^T + h   (in-place over resid: safe, each elem read->written by same thread)
    gemm_nt_kernel<<<ggrid, 256, 0, stream>>>(ws0, Wo + (size_t)l * nD * nD, nullptr, h, h);
    ln_kernel<<<nTOK, 256, 0, stream>>>(h, g1 + l * nD, be1 + l * nD, h);   // n1 (in-place)
    // t2 = n1 @ Wfc^T + bfc + n1
    gemm_nt_kernel<<<ggrid, 256, 0, stream>>>(h, Wfc + (size_t)l * nD * nD, bfc + l * nD, h, ws0);
    ln_kernel<<<nTOK, 256, 0, stream>>>(ws0, g2 + l * nD, be2 + l * nD, h); // new h
  }
  (void)in_sizes; (void)n_in; (void)out_size; (void)ws_size;
}

// Round 2
// 3289.268 us; speedup vs baseline: 1.8559x; 1.8559x over previous
//
#include <hip/hip_runtime.h>
#include <hip/hip_bf16.h>
#include <math.h>

constexpr int nB = 1024, nS = 30, nE = 300, nD = 512, nH = 8, nL = 4, nDK = 64;
constexpr int nTOK = nB * nS;  // 30720
constexpr float kSqrtD = 22.627416997969522f;       // sqrt(512)
constexpr float kPEc   = -0.03597789207803244f;     // -2*ln(10000)/512

struct alignas(8) bf16x4 { __hip_bfloat16 v[4]; };

__device__ inline float4 load4f(const float* p) { return *(const float4*)p; }
__device__ inline float4 load4f(const __hip_bfloat16* p) {
  const bf16x4 u = *(const bf16x4*)p;
  return make_float4(__bfloat162float(u.v[0]), __bfloat162float(u.v[1]),
                     __bfloat162float(u.v[2]), __bfloat162float(u.v[3]));
}
__device__ inline void store4bf(__hip_bfloat16* p, float a, float b, float c, float d) {
  bf16x4 u{{__float2bfloat16(a), __float2bfloat16(b), __float2bfloat16(c), __float2bfloat16(d)}};
  *(bf16x4*)p = u;
}

// ---------------- embedding gather + input projection + posenc ----------------
constexpr int TPB_EMB = 8;
__global__ __launch_bounds__(256) void embed_kernel(
    const int* __restrict__ x, const float* __restrict__ emb,
    const float* __restrict__ W_in, const float* __restrict__ b_in,
    float* __restrict__ h) {
  const int tid = threadIdx.x;
  const int t0 = blockIdx.x * TPB_EMB;
  __shared__ float er[TPB_EMB][nE];
  for (int idx = tid; idx < TPB_EMB * nE; idx += 256) {
    int r = idx / nE, e = idx - r * nE;
    er[r][e] = emb[(size_t)x[t0 + r] * nE + e];
  }
  __syncthreads();
  for (int d = tid; d < nD; d += 256) {
    const float* w = W_in + (size_t)d * nE;
    float acc[TPB_EMB] = {};
    for (int e = 0; e < nE; e += 4) {
      const float4 wv = *(const float4*)(w + e);
#pragma unroll
      for (int r = 0; r < TPB_EMB; ++r) {
        const float4 ev = *(const float4*)&er[r][e];
        acc[r] += ev.x * wv.x + ev.y * wv.y + ev.z * wv.z + ev.w * wv.w;
      }
    }
    const float bias = b_in[d];
    const float dv = expf((float)(d >> 1) * kPEc);
#pragma unroll
    for (int r = 0; r < TPB_EMB; ++r) {
      const int t = t0 + r;
      const int s = t % nS;
      const float ang = (float)s * dv;
      const float pe = (d & 1) ? cosf(ang) : sinf(ang);
      h[(size_t)t * nD + d] = (acc[r] + bias) * kSqrtD + pe;
    }
  }
}

// ---------------- QKV projection: shared 64x64 per-head weight = thin GEMM ----------------
// out layout: [B, H, S, DK] bf16
constexpr int QKV_TPB = 8;  // tokens per block
__global__ __launch_bounds__(128) void qkv_kernel(
    const float* __restrict__ h, const float* __restrict__ Wq,
    const float* __restrict__ Wk, const float* __restrict__ Wv,
    __hip_bfloat16* __restrict__ Q, __hip_bfloat16* __restrict__ K,
    __hip_bfloat16* __restrict__ V) {
  const int tid = threadIdx.x;
  const int t0 = blockIdx.x * QKV_TPB;
  __shared__ float xs[QKV_TPB][544];  // 8 head-chunks of 68 (skew 4 banks/head)
  for (int idx = tid; idx < QKV_TPB * 128; idx += 128) {
    const int t = idx >> 7, c = idx & 127;  // c = float4 index within row
    const int hh = c >> 4, w = c & 15;
    const float4 v4 = *(const float4*)(h + (size_t)(t0 + t) * nD + c * 4);
    *(float4*)&xs[t][hh * 68 + w * 4] = v4;
  }
  __syncthreads();
  const int hd = tid >> 4, dq = tid & 15;
  const int d0 = dq << 2;
  const float* Ws[3] = {Wq, Wk, Wv};
  __hip_bfloat16* Os[3] = {Q, K, V};
  for (int m = 0; m < 3; ++m) {
    const float* W = Ws[m];
    float acc[QKV_TPB][4] = {};
    for (int k4 = 0; k4 < nDK; k4 += 4) {
      float4 w4[4];
#pragma unroll
      for (int i = 0; i < 4; ++i) w4[i] = *(const float4*)(W + (d0 + i) * nDK + k4);
#pragma unroll
      for (int t = 0; t < QKV_TPB; ++t) {
        const float4 x4 = *(const float4*)&xs[t][hd * 68 + k4];
#pragma unroll
        for (int i = 0; i < 4; ++i)
          acc[t][i] += x4.x * w4[i].x + x4.y * w4[i].y + x4.z * w4[i].z + x4.w * w4[i].w;
      }
    }
    __hip_bfloat16* Om = Os[m];
#pragma unroll
    for (int t = 0; t < QKV_TPB; ++t) {
      const int tok = t0 + t;
      const int b = tok / nS, s = tok - b * nS;
      const size_t off = (((size_t)(b * nH + hd)) * nS + s) * nDK + d0;
      store4bf(Om + off, acc[t][0], acc[t][1], acc[t][2], acc[t][3]);
    }
  }
}

// ---------------- attention core per (b, head): scores -> softmax -> PV ----------------
// O layout: [B, S, H, DK] bf16 (i.e. the [B,S,D] activation)
__global__ __launch_bounds__(256) void attn_core_kernel(
    const __hip_bfloat16* __restrict__ Q, const __hip_bfloat16* __restrict__ K,
    const __hip_bfloat16* __restrict__ V, const int* __restrict__ mask,
    __hip_bfloat16* __restrict__ O) {
  const int tid = threadIdx.x;
  const int b = blockIdx.x >> 3, hd = blockIdx.x & 7;
  __shared__ float sQ[nS][68];
  __shared__ float sK[32][68];   // rows 30,31 read (discarded) by score loop
  __shared__ float sV[nS][68];
  __shared__ float ps[nS][33];
  __shared__ int msk[32];
  const size_t base = ((size_t)(b * nH + hd)) * nS * nDK;
  for (int idx = tid; idx < nS * 16; idx += 256) {
    const int s = idx >> 4, c = (idx & 15) << 2;
    *(float4*)&sQ[s][c] = load4f(Q + base + s * nDK + c);
    *(float4*)&sK[s][c] = load4f(K + base + s * nDK + c);
    *(float4*)&sV[s][c] = load4f(V + base + s * nDK + c);
  }
  if (tid < nS) msk[tid] = mask[b * nS + tid];
  __syncthreads();

  // scores = q k^T / 8, masked
  {
    const int i = tid >> 3, j0 = (tid & 7) << 2;
    if (i < nS) {
      float acc[4] = {};
#pragma unroll
      for (int d4 = 0; d4 < nDK; d4 += 4) {
        const float4 q4 = *(const float4*)&sQ[i][d4];
#pragma unroll
        for (int jj = 0; jj < 4; ++jj) {
          const float4 k4 = *(const float4*)&sK[j0 + jj][d4];
          acc[jj] += q4.x * k4.x + q4.y * k4.y + q4.z * k4.z + q4.w * k4.w;
        }
      }
#pragma unroll
      for (int jj = 0; jj < 4; ++jj) {
        const int j = j0 + jj;
        if (j < nS) ps[i][j] = (msk[j] == 0) ? -1e9f : acc[jj] * 0.125f;
      }
    }
  }
  __syncthreads();

  // softmax: 8 lanes per row
  if (tid < nS * 8) {
    const int r = tid >> 3, c = tid & 7;
    float m = -1e30f;
    for (int j = c; j < nS; j += 8) m = fmaxf(m, ps[r][j]);
#pragma unroll
    for (int off = 1; off < 8; off <<= 1) m = fmaxf(m, __shfl_xor(m, off));
    float sum = 0.f;
    for (int j = c; j < nS; j += 8) {
      const float e = __expf(ps[r][j] - m);
      ps[r][j] = e;
      sum += e;
    }
#pragma unroll
    for (int off = 1; off < 8; off <<= 1) sum += __shfl_xor(sum, off);
    const float inv = 1.f / sum;
    for (int j = c; j < nS; j += 8) ps[r][j] *= inv;
  }
  __syncthreads();

  // o = p @ v  -> O[b, s, hd, :]
  {
    const int sg = tid >> 4, dg = tid & 15;
    const int d0 = dg << 2;
    const bool has2 = (sg + 16) < nS;
    float a0[4] = {}, a1[4] = {};
#pragma unroll
    for (int j = 0; j < nS; ++j) {
      const float4 vv = *(const float4*)&sV[j][d0];
      const float p0 = ps[sg][j];
      const float p1 = has2 ? ps[sg + 16][j] : 0.f;
      a0[0] += p0 * vv.x; a0[1] += p0 * vv.y; a0[2] += p0 * vv.z; a0[3] += p0 * vv.w;
      a1[0] += p1 * vv.x; a1[1] += p1 * vv.y; a1[2] += p1 * vv.z; a1[3] += p1 * vv.w;
    }
    store4bf(O + (((size_t)(b * nS + sg)) * nH + hd) * nDK + d0, a0[0], a0[1], a0[2], a0[3]);
    if (has2)
      store4bf(O + (((size_t)(b * nS + sg + 16)) * nH + hd) * nDK + d0, a1[0], a1[1], a1[2], a1[3]);
  }
}

// ---------------- tiled NT GEMM: C[t,n] = sum_k A[t,k]*W[n,k] (+bias)(+resid) ----------------
template <typename TA>
__global__ __launch_bounds__(256) void gemm_nt_kernel(
    const TA* __restrict__ A, const float* __restrict__ W,
    const float* __restrict__ bias, const float* __restrict__ resid,
    float* __restrict__ C) {
  __shared__ float As[16][68];
  __shared__ float Ws[16][68];
  const int tid = threadIdx.x;
  const int bm = blockIdx.x, bn = blockIdx.y;
  const int tx = tid & 15, ty = tid >> 4;
  const int lr = tid >> 2, lc = (tid & 3) << 2;
  const TA* Ag = A + (size_t)(bm * 64 + lr) * nD + lc;
  const float* Wg = W + (size_t)(bn * 64 + lr) * nD + lc;
  float acc[4][4] = {};
  for (int k0 = 0; k0 < nD; k0 += 16) {
    const float4 av = load4f(Ag + k0);
    const float4 wv = *(const float4*)(Wg + k0);
    __syncthreads();
    As[lc + 0][lr] = av.x; As[lc + 1][lr] = av.y; As[lc + 2][lr] = av.z; As[lc + 3][lr] = av.w;
    Ws[lc + 0][lr] = wv.x; Ws[lc + 1][lr] = wv.y; Ws[lc + 2][lr] = wv.z; Ws[lc + 3][lr] = wv.w;
    __syncthreads();
#pragma unroll
    for (int k = 0; k < 16; ++k) {
      const float4 a = *(const float4*)&As[k][ty << 2];
      const float4 w = *(const float4*)&Ws[k][tx << 2];
      const float aa[4] = {a.x, a.y, a.z, a.w};
      const float ww[4] = {w.x, w.y, w.z, w.w};
#pragma unroll
      for (int i = 0; i < 4; ++i)
#pragma unroll
        for (int j = 0; j < 4; ++j)
          acc[i][j] += aa[i] * ww[j];
    }
  }
  const int gr0 = bm * 64 + (ty << 2);
  const int gc = bn * 64 + (tx << 2);
#pragma unroll
  for (int i = 0; i < 4; ++i) {
    const size_t off = (size_t)(gr0 + i) * nD + gc;
    float4 o = make_float4(acc[i][0], acc[i][1], acc[i][2], acc[i][3]);
    if (bias) { o.x += bias[gc]; o.y += bias[gc + 1]; o.z += bias[gc + 2]; o.w += bias[gc + 3]; }
    if (resid) {
      const float4 rs = *(const float4*)(resid + off);
      o.x += rs.x; o.y += rs.y; o.z += rs.z; o.w += rs.w;
    }
    *(float4*)(C + off) = o;
  }
}

// ---------------- row LayerNorm over D=512 ----------------
__global__ __launch_bounds__(256) void ln_kernel(
    const float* __restrict__ X, const float* __restrict__ g,
    const float* __restrict__ bta, float* __restrict__ Y) {
  const int t = blockIdx.x, tid = threadIdx.x;
  const float2 v = *(const float2*)(X + (size_t)t * nD + tid * 2);
  __shared__ float red[4];
  float s = v.x + v.y;
#pragma unroll
  for (int off = 32; off >= 1; off >>= 1) s += __shfl_down(s, off);
  if ((tid & 63) == 0) red[tid >> 6] = s;
  __syncthreads();
  const float mu = (red[0] + red[1] + red[2] + red[3]) * (1.0f / nD);
  const float e0 = v.x - mu, e1 = v.y - mu;
  float sq = e0 * e0 + e1 * e1;
  __syncthreads();
#pragma unroll
  for (int off = 32; off >= 1; off >>= 1) sq += __shfl_down(sq, off);
  if ((tid & 63) == 0) red[tid >> 6] = sq;
  __syncthreads();
  const float var = (red[0] + red[1] + red[2] + red[3]) * (1.0f / nD);
  const float inv = rsqrtf(var + 1e-5f);
  const float2 gg = *(const float2*)(g + tid * 2);
  const float2 bb = *(const float2*)(bta + tid * 2);
  float2 o;
  o.x = e0 * inv * gg.x + bb.x;
  o.y = e1 * inv * gg.y + bb.y;
  *(float2*)(Y + (size_t)t * nD + tid * 2) = o;
}

extern "C" void kernel_launch(void* const* d_in, const int* in_sizes, int n_in,
                              void* d_out, int out_size, void* d_ws, size_t ws_size,
                              hipStream_t stream) {
  const int*   x    = (const int*)d_in[0];
  const int*   mask = (const int*)d_in[1];
  const float* emb  = (const float*)d_in[2];
  const float* W_in = (const float*)d_in[3];
  const float* b_in = (const float*)d_in[4];
  const float* Wq   = (const float*)d_in[5];
  const float* Wk   = (const float*)d_in[6];
  const float* Wv   = (const float*)d_in[7];
  const float* Wo   = (const float*)d_in[8];
  const float* Wfc  = (const float*)d_in[9];
  const float* bfc  = (const float*)d_in[10];
  const float* g1   = (const float*)d_in[11];
  const float* be1  = (const float*)d_in[12];
  const float* g2   = (const float*)d_in[13];
  const float* be2  = (const float*)d_in[14];
  float* h = (float*)d_out;                 // h lives in d_out across layers

  const size_t NQ = (size_t)nB * nH * nS * nDK;  // 15,728,640
  __hip_bfloat16* Qb = (__hip_bfloat16*)d_ws;
  __hip_bfloat16* Kb = Qb + NQ;
  __hip_bfloat16* Vb = Qb + 2 * NQ;
  __hip_bfloat16* Ob = Qb + 3 * NQ;
  float* fcout = (float*)d_ws;              // reuses dead Q+K region (63 MB)

  embed_kernel<<<nTOK / TPB_EMB, 256, 0, stream>>>(x, emb, W_in, b_in, h);
  const dim3 ggrid(nTOK / 64, nD / 64);
  for (int l = 0; l < nL; ++l) {
    qkv_kernel<<<nTOK / QKV_TPB, 128, 0, stream>>>(
        h, Wq + (size_t)l * nDK * nDK, Wk + (size_t)l * nDK * nDK,
        Wv + (size_t)l * nDK * nDK, Qb, Kb, Vb);
    attn_core_kernel<<<nB * nH, 256, 0, stream>>>(Qb, Kb, Vb, mask, Ob);
    // t1 = attn_out @ Wo^T + h  (in-place over resid: each elem read->written by same thread)
    gemm_nt_kernel<__hip_bfloat16><<<ggrid, 256, 0, stream>>>(
        Ob, Wo + (size_t)l * nD * nD, nullptr, h, h);
    ln_kernel<<<nTOK, 256, 0, stream>>>(h, g1 + l * nD, be1 + l * nD, h);   // n1 (in-place)
    // t2 = n1 @ Wfc^T + bfc + n1   (fcout overwrites dead Q/K region)
    gemm_nt_kernel<float><<<ggrid, 256, 0, stream>>>(
        h, Wfc + (size_t)l * nD * nD, bfc + l * nD, h, fcout);
    ln_kernel<<<nTOK, 256, 0, stream>>>(fcout, g2 + l * nD, be2 + l * nD, h); // new h
  }
  (void)in_sizes; (void)n_in; (void)out_size; (void)ws_size;
}

// Round 3
// 695.688 us; speedup vs baseline: 8.7747x; 4.7281x over previous
//
#include <hip/hip_runtime.h>
#include <hip/hip_bf16.h>
#include <math.h>

using bf16 = __hip_bfloat16;
typedef __attribute__((ext_vector_type(8))) short short8;
typedef __attribute__((ext_vector_type(4))) float f32x4;

constexpr int nB = 1024, nS = 30, nE = 300, nD = 512, nH = 8, nL = 4, nDK = 64;
constexpr int nTOK = nB * nS;  // 30720
constexpr float kSqrtD = 22.627416997969522f;    // sqrt(512)
constexpr float kPEc   = -0.03597789207803244f;  // -2*ln(10000)/512

__device__ inline unsigned short bfbits(float f) {
  bf16 h = __float2bfloat16(f);
  return *(unsigned short*)&h;
}
__device__ inline void gload16(const void* g, void* lds) {
  __builtin_amdgcn_global_load_lds(
      (const __attribute__((address_space(1))) unsigned int*)g,
      (__attribute__((address_space(3))) unsigned int*)lds, 16, 0, 0);
}

// ---------------- small converters ----------------
__global__ __launch_bounds__(256) void cvt_kernel(const float* __restrict__ s,
                                                  bf16* __restrict__ d, int n4) {
  int i = blockIdx.x * 256 + threadIdx.x;
  if (i < n4) {
    float4 v = ((const float4*)s)[i];
    ushort4 u;
    u.x = bfbits(v.x); u.y = bfbits(v.y); u.z = bfbits(v.z); u.w = bfbits(v.w);
    ((ushort4*)d)[i] = u;
  }
}

__global__ __launch_bounds__(256) void cvt_pad_win(const float* __restrict__ s,
                                                   bf16* __restrict__ d) {
  int row = blockIdx.x;  // 512
  for (int e = threadIdx.x; e < 320; e += 256)
    d[row * 320 + e] = __float2bfloat16((e < nE) ? s[row * nE + e] : 0.f);
}

__global__ __launch_bounds__(256) void pe_kernel(float* __restrict__ pe) {
  int s = blockIdx.x;  // 30
  for (int dd = threadIdx.x; dd < nD; dd += 256) {
    float ang = (float)s * expf((float)(dd >> 1) * kPEc);
    pe[s * nD + dd] = (dd & 1) ? cosf(ang) : sinf(ang);
  }
}

// gather emb rows -> bf16 [nTOK][320] (K padded 300->320 with zeros)
__global__ __launch_bounds__(256) void gather_kernel(const int* __restrict__ x,
                                                     const float* __restrict__ emb,
                                                     bf16* __restrict__ a) {
  int g = blockIdx.x * 256 + threadIdx.x;  // 30720*40 slots
  int t = g / 40, ch = g - 40 * t;
  float4 v0 = make_float4(0.f, 0.f, 0.f, 0.f), v1 = v0;
  const float* src = emb + (size_t)x[t] * nE + ch * 8;
  if (ch < 37) { v0 = *(const float4*)src; v1 = *(const float4*)(src + 4); }
  else if (ch == 37) { v0 = *(const float4*)src; }
  ushort4 u0, u1;
  u0.x = bfbits(v0.x); u0.y = bfbits(v0.y); u0.z = bfbits(v0.z); u0.w = bfbits(v0.w);
  u1.x = bfbits(v1.x); u1.y = bfbits(v1.y); u1.z = bfbits(v1.z); u1.w = bfbits(v1.w);
  bf16* dst = a + (size_t)t * 320 + ch * 8;
  *(ushort4*)dst = u0;
  *(ushort4*)(dst + 4) = u1;
}

// ---------------- fused MFMA GEMM: C[M,512] = A[M,KA](bf16) @ W[512,KA](bf16)^T ----------------
// EPI 0: y = (acc + bias)*sqrtD + pe[row%30][col]          (embed)
// EPI 1: y = LN(acc + bias? + resid)[g,beta]               (transformer)
// Writes fp32 (outf) and bf16 (outb) copies, coalesced via LDS transpose.
template <int KA, int EPI>
__global__ __launch_bounds__(256, 2) void gemm_fused(
    const bf16* __restrict__ A, const bf16* __restrict__ W,
    const float* __restrict__ bias, const float* __restrict__ resid,
    const float* __restrict__ pe, const float* __restrict__ g,
    const float* __restrict__ beta, float* __restrict__ outf,
    bf16* __restrict__ outb) {
  __shared__ __align__(16) char smem[39424];
  bf16* As = (bf16*)smem;            // [4][64][8] chunked: elem ((kc*64+row)*8 + e)
  bf16* Ws = (bf16*)smem + 2048;     // [4][512][8]
  float* tb = (float*)smem;          // epilogue transpose, wave w: [w*2048 .. +2048)
  float* stats = (float*)(smem + 36864);   // [64][4][2]
  float* stats2 = (float*)(smem + 38912);  // [64][2] (mu, inv)

  const int tid = threadIdx.x, lane = tid & 63, w = tid >> 6;
  const int q = lane >> 4, c = lane & 15;
  const int m0 = blockIdx.x * 64;

  f32x4 acc[4][8];
#pragma unroll
  for (int i = 0; i < 4; ++i)
#pragma unroll
    for (int j = 0; j < 8; ++j) acc[i][j] = (f32x4){0.f, 0.f, 0.f, 0.f};

  const bf16* Ag = A + (size_t)(m0 + lane) * KA + w * 8;  // row m0+lane, k-chunk w
  const bf16* Wg = W + (size_t)lane * KA + w * 8;
  bf16* AsDst = As + (w * 64) * 8;
  bf16* WsDst = Ws + (w * 512) * 8;

  for (int ks = 0; ks < KA / 32; ++ks) {
    __syncthreads();
    gload16(Ag + ks * 32, AsDst);
#pragma unroll
    for (int j = 0; j < 8; ++j)
      gload16(Wg + (size_t)(j * 64) * KA + ks * 32, WsDst + j * 64 * 8);
    __syncthreads();
    short8 af[4], bfr[8];
#pragma unroll
    for (int mt = 0; mt < 4; ++mt)
      af[mt] = *(const short8*)(As + (q * 64 + mt * 16 + c) * 8);
#pragma unroll
    for (int nt = 0; nt < 8; ++nt)
      bfr[nt] = *(const short8*)(Ws + (q * 512 + w * 128 + nt * 16 + c) * 8);
#pragma unroll
    for (int mt = 0; mt < 4; ++mt)
#pragma unroll
      for (int nt = 0; nt < 8; ++nt)
        acc[mt][nt] = __builtin_amdgcn_mfma_f32_16x16x32_bf16(af[mt], bfr[nt], acc[mt][nt], 0, 0, 0);
  }

  // ---- epilogue ----
  float bias4[8];
#pragma unroll
  for (int nt = 0; nt < 8; ++nt)
    bias4[nt] = bias ? bias[w * 128 + nt * 16 + c] : 0.f;

  if (EPI == 0) {
#pragma unroll
    for (int mt = 0; mt < 4; ++mt)
#pragma unroll
      for (int r = 0; r < 4; ++r) {
        int m = m0 + mt * 16 + q * 4 + r;
        int s = m % nS;
        const float* pes = pe + (size_t)s * nD + w * 128 + c;
#pragma unroll
        for (int nt = 0; nt < 8; ++nt)
          acc[mt][nt][r] = (acc[mt][nt][r] + bias4[nt]) * kSqrtD + pes[nt * 16];
      }
    __syncthreads();  // LDS now free for transpose reuse
  } else {
    float rs[4][4], rq[4][4];
#pragma unroll
    for (int mt = 0; mt < 4; ++mt)
#pragma unroll
      for (int r = 0; r < 4; ++r) {
        int m = m0 + mt * 16 + q * 4 + r;
        const float* rp = resid + (size_t)m * nD + w * 128 + c;
        float s1 = 0.f, s2 = 0.f;
#pragma unroll
        for (int nt = 0; nt < 8; ++nt) {
          float t = acc[mt][nt][r] + bias4[nt] + rp[nt * 16];
          acc[mt][nt][r] = t;
          s1 += t; s2 += t * t;
        }
        rs[mt][r] = s1; rq[mt][r] = s2;
      }
#pragma unroll
    for (int mt = 0; mt < 4; ++mt)
#pragma unroll
      for (int r = 0; r < 4; ++r)
#pragma unroll
        for (int off = 1; off < 16; off <<= 1) {
          rs[mt][r] += __shfl_xor(rs[mt][r], off);
          rq[mt][r] += __shfl_xor(rq[mt][r], off);
        }
#pragma unroll
    for (int mt = 0; mt < 4; ++mt)
#pragma unroll
      for (int r = 0; r < 4; ++r)
        if (c == mt * 4 + r) {
          int row = mt * 16 + q * 4 + r;
          stats[row * 8 + w * 2] = rs[mt][r];
          stats[row * 8 + w * 2 + 1] = rq[mt][r];
        }
    __syncthreads();
    if (tid < 64) {
      float su = 0.f, sq = 0.f;
#pragma unroll
      for (int ww = 0; ww < 4; ++ww) {
        su += stats[tid * 8 + ww * 2];
        sq += stats[tid * 8 + ww * 2 + 1];
      }
      float mu = su * (1.f / nD);
      float var = sq * (1.f / nD) - mu * mu;
      stats2[tid * 2] = mu;
      stats2[tid * 2 + 1] = rsqrtf(var + 1e-5f);
    }
    __syncthreads();
  }

  // transpose + coalesced dual store
  float* tbw = tb + w * 2048;
  const int l32 = lane & 31, hi = lane >> 5;
  const int colw = w * 128 + l32 * 4;
  float4 g4 = make_float4(0, 0, 0, 0), be4 = g4;
  if (EPI == 1) {
    g4 = *(const float4*)&g[colw];
    be4 = *(const float4*)&beta[colw];
  }
#pragma unroll
  for (int mt = 0; mt < 4; ++mt) {
#pragma unroll
    for (int nt = 0; nt < 8; ++nt)
#pragma unroll
      for (int r = 0; r < 4; ++r)
        tbw[(q * 4 + r) * 128 + nt * 16 + c] = acc[mt][nt][r];
#pragma unroll
    for (int i = 0; i < 8; ++i) {
      float4 v = *(const float4*)&tbw[(i * 64 + lane) * 4];
      int rl = mt * 16 + i * 2 + hi;
      int m = m0 + rl;
      float4 y;
      if (EPI == 1) {
        float mu = stats2[rl * 2], inv = stats2[rl * 2 + 1];
        y.x = (v.x - mu) * inv * g4.x + be4.x;
        y.y = (v.y - mu) * inv * g4.y + be4.y;
        y.z = (v.z - mu) * inv * g4.z + be4.z;
        y.w = (v.w - mu) * inv * g4.w + be4.w;
      } else {
        y = v;
      }
      *(float4*)(outf + (size_t)m * nD + colw) = y;
      ushort4 ub;
      ub.x = bfbits(y.x); ub.y = bfbits(y.y); ub.z = bfbits(y.z); ub.w = bfbits(y.w);
      *(ushort4*)(outb + (size_t)m * nD + colw) = ub;
    }
  }
}

// ---------------- fully fused attention per (batch, head), MFMA, in-place on hb ----------------
__global__ __launch_bounds__(256) void attn_kernel(
    const bf16* __restrict__ wqb, const bf16* __restrict__ wkb,
    const bf16* __restrict__ wvb, const int* __restrict__ mask,
    bf16* __restrict__ hb) {
  const int tid = threadIdx.x, lane = tid & 63, w = tid >> 6;
  const int q = lane >> 4, c = lane & 15;
  const int b = blockIdx.x >> 3, hd = blockIdx.x & 7;

  __shared__ __align__(16) bf16 xs[8][32][8];   // x slice, chunked by k/8
  __shared__ __align__(16) bf16 wq[8][64][8];
  __shared__ __align__(16) bf16 wk[8][64][8];
  __shared__ __align__(16) bf16 wv[8][64][8];
  __shared__ __align__(16) bf16 qb[8][32][8];   // q chunked by dk/8
  __shared__ __align__(16) bf16 kb[8][32][8];
  __shared__ __align__(16) bf16 vt[4][64][8];   // V^T: [j/8][d][j%8]
  __shared__ __align__(16) bf16 pb[4][32][8];   // probs: [j/8][i][j%8]
  __shared__ float ps[32][33];
  __shared__ int msk[32];

  {  // stage x (pad rows 30,31 with zeros)
    int row = tid & 31, k8 = tid >> 5;
    uint4 z = make_uint4(0, 0, 0, 0);
    if (row < nS)
      z = *(const uint4*)(hb + (size_t)(b * nS + row) * nD + hd * nDK + k8 * 8);
    *(uint4*)&xs[k8][row][0] = z;
  }
#pragma unroll
  for (int i = 0; i < 2; ++i) {  // stage weights
    int s = tid + i * 256;
    int row = s & 63, k8 = s >> 6;
    *(uint4*)&wq[k8][row][0] = *(const uint4*)(wqb + row * 64 + k8 * 8);
    *(uint4*)&wk[k8][row][0] = *(const uint4*)(wkb + row * 64 + k8 * 8);
    *(uint4*)&wv[k8][row][0] = *(const uint4*)(wvb + row * 64 + k8 * 8);
  }
  if (tid < nS) msk[tid] = mask[b * nS + tid];
  __syncthreads();

  // q/k/v projections: wave w -> output cols [w*16, w*16+16)
  f32x4 aq[2], ak[2], av[2];
#pragma unroll
  for (int mt = 0; mt < 2; ++mt) {
    aq[mt] = (f32x4){0.f, 0.f, 0.f, 0.f};
    ak[mt] = aq[mt]; av[mt] = aq[mt];
  }
#pragma unroll
  for (int kc = 0; kc < 2; ++kc) {
    short8 xa0 = *(const short8*)&xs[kc * 4 + q][c][0];
    short8 xa1 = *(const short8*)&xs[kc * 4 + q][16 + c][0];
    short8 wqf = *(const short8*)&wq[kc * 4 + q][w * 16 + c][0];
    short8 wkf = *(const short8*)&wk[kc * 4 + q][w * 16 + c][0];
    short8 wvf = *(const short8*)&wv[kc * 4 + q][w * 16 + c][0];
    aq[0] = __builtin_amdgcn_mfma_f32_16x16x32_bf16(xa0, wqf, aq[0], 0, 0, 0);
    aq[1] = __builtin_amdgcn_mfma_f32_16x16x32_bf16(xa1, wqf, aq[1], 0, 0, 0);
    ak[0] = __builtin_amdgcn_mfma_f32_16x16x32_bf16(xa0, wkf, ak[0], 0, 0, 0);
    ak[1] = __builtin_amdgcn_mfma_f32_16x16x32_bf16(xa1, wkf, ak[1], 0, 0, 0);
    av[0] = __builtin_amdgcn_mfma_f32_16x16x32_bf16(xa0, wvf, av[0], 0, 0, 0);
    av[1] = __builtin_amdgcn_mfma_f32_16x16x32_bf16(xa1, wvf, av[1], 0, 0, 0);
  }
  const int dk = w * 16 + c;
#pragma unroll
  for (int mt = 0; mt < 2; ++mt)
#pragma unroll
    for (int r = 0; r < 4; ++r) {
      int i = mt * 16 + q * 4 + r;
      qb[dk >> 3][i][dk & 7] = __float2bfloat16(aq[mt][r]);
      kb[dk >> 3][i][dk & 7] = __float2bfloat16(ak[mt][r]);
      vt[i >> 3][dk][i & 7] = __float2bfloat16(av[mt][r]);
    }
  __syncthreads();

  // scores: wave w -> row-block w>>1, col-block w&1
  {
    f32x4 sc = (f32x4){0.f, 0.f, 0.f, 0.f};
    const int is0 = (w >> 1) * 16, js0 = (w & 1) * 16;
#pragma unroll
    for (int kc = 0; kc < 2; ++kc) {
      short8 a = *(const short8*)&qb[kc * 4 + q][is0 + c][0];
      short8 bb = *(const short8*)&kb[kc * 4 + q][js0 + c][0];
      sc = __builtin_amdgcn_mfma_f32_16x16x32_bf16(a, bb, sc, 0, 0, 0);
    }
    int j = js0 + c;
    bool live = (j < nS) && (msk[j] != 0);
#pragma unroll
    for (int r = 0; r < 4; ++r) {
      int i = is0 + q * 4 + r;
      ps[i][j] = live ? sc[r] * 0.125f : -1e9f;
    }
  }
  __syncthreads();

  // softmax (rows < 30), 8 lanes per row
  if (tid < nS * 8) {
    int r = tid >> 3, cc = tid & 7;
    float m = -1e30f;
    for (int j = cc; j < nS; j += 8) m = fmaxf(m, ps[r][j]);
#pragma unroll
    for (int o = 1; o < 8; o <<= 1) m = fmaxf(m, __shfl_xor(m, o));
    float sum = 0.f;
    for (int j = cc; j < nS; j += 8) sum += __expf(ps[r][j] - m);
#pragma unroll
    for (int o = 1; o < 8; o <<= 1) sum += __shfl_xor(sum, o);
    float inv = 1.f / sum;
    for (int j = cc; j < nS; j += 8)
      pb[j >> 3][r][j & 7] = __float2bfloat16(__expf(ps[r][j] - m) * inv);
    if (cc >= 6) pb[3][r][cc] = __float2bfloat16(0.f);  // zero k-slots j=30,31
  }
  __syncthreads();

  // PV: wave w -> d-cols [w*16, w*16+16)
  {
    f32x4 o0 = (f32x4){0.f, 0.f, 0.f, 0.f}, o1 = o0;
    short8 pa0 = *(const short8*)&pb[q][c][0];
    short8 pa1 = *(const short8*)&pb[q][16 + c][0];
    short8 vb = *(const short8*)&vt[q][w * 16 + c][0];
    o0 = __builtin_amdgcn_mfma_f32_16x16x32_bf16(pa0, vb, o0, 0, 0, 0);
    o1 = __builtin_amdgcn_mfma_f32_16x16x32_bf16(pa1, vb, o1, 0, 0, 0);
#pragma unroll
    for (int r = 0; r < 4; ++r) {
      int i0 = q * 4 + r;
      hb[(size_t)(b * nS + i0) * nD + hd * nDK + dk] = __float2bfloat16(o0[r]);
      int i1 = 16 + q * 4 + r;
      if (i1 < nS)
        hb[(size_t)(b * nS + i1) * nD + hd * nDK + dk] = __float2bfloat16(o1[r]);
    }
  }
}

extern "C" void kernel_launch(void* const* d_in, const int* in_sizes, int n_in,
                              void* d_out, int out_size, void* d_ws, size_t ws_size,
                              hipStream_t stream) {
  const int*   x    = (const int*)d_in[0];
  const int*   mask = (const int*)d_in[1];
  const float* emb  = (const float*)d_in[2];
  const float* W_in = (const float*)d_in[3];
  const float* b_in = (const float*)d_in[4];
  const float* Wq   = (const float*)d_in[5];
  const float* Wk   = (const float*)d_in[6];
  const float* Wv   = (const float*)d_in[7];
  const float* Wo   = (const float*)d_in[8];
  const float* Wfc  = (const float*)d_in[9];
  const float* bfc  = (const float*)d_in[10];
  const float* g1   = (const float*)d_in[11];
  const float* be1  = (const float*)d_in[12];
  const float* g2   = (const float*)d_in[13];
  const float* be2  = (const float*)d_in[14];
  float* h = (float*)d_out;  // fp32 activation/residual stream

  char* ws = (char*)d_ws;
  bf16* wo_b  = (bf16*)ws;                  // 4 * 512*512
  bf16* wfc_b = (bf16*)(ws + 2097152);      // 4 * 512*512
  bf16* wq_b  = (bf16*)(ws + 4194304);      // 4 * 64*64
  bf16* wk_b  = (bf16*)(ws + 4227072);
  bf16* wv_b  = (bf16*)(ws + 4259840);
  bf16* win_b = (bf16*)(ws + 4292608);      // [512][320]
  float* pe   = (float*)(ws + 4620288);     // [30][512]
  bf16* a_emb = (bf16*)(ws + 4681728);      // [30720][320]
  bf16* hb    = (bf16*)(ws + 24342528);     // [30720][512] bf16 activation copy

  cvt_kernel<<<1024, 256, 0, stream>>>(Wo, wo_b, 262144);
  cvt_kernel<<<1024, 256, 0, stream>>>(Wfc, wfc_b, 262144);
  cvt_kernel<<<16, 256, 0, stream>>>(Wq, wq_b, 4096);
  cvt_kernel<<<16, 256, 0, stream>>>(Wk, wk_b, 4096);
  cvt_kernel<<<16, 256, 0, stream>>>(Wv, wv_b, 4096);
  cvt_pad_win<<<512, 256, 0, stream>>>(W_in, win_b);
  pe_kernel<<<30, 256, 0, stream>>>(pe);
  gather_kernel<<<4800, 256, 0, stream>>>(x, emb, a_emb);

  gemm_fused<320, 0><<<480, 256, 0, stream>>>(a_emb, win_b, b_in, nullptr, pe,
                                              nullptr, nullptr, h, hb);
  for (int l = 0; l < nL; ++l) {
    attn_kernel<<<nB * nH, 256, 0, stream>>>(wq_b + l * 4096, wk_b + l * 4096,
                                             wv_b + l * 4096, mask, hb);
    gemm_fused<512, 1><<<480, 256, 0, stream>>>(hb, wo_b + (size_t)l * 262144,
                                                nullptr, h, nullptr, g1 + l * nD,
                                                be1 + l * nD, h, hb);
    gemm_fused<512, 1><<<480, 256, 0, stream>>>(hb, wfc_b + (size_t)l * 262144,
                                                bfc + l * nD, h, nullptr, g2 + l * nD,
                                                be2 + l * nD, h, hb);
  }
  (void)in_sizes; (void)n_in; (void)out_size; (void)ws_size;
}